// Round 1
// baseline (331.800 us; speedup 1.0000x reference)
//
#include <hip/hip_runtime.h>

#define T_LEN 2048
#define B_SZ  512
#define NIN   27

__device__ __forceinline__ float fast_exp2(float x) { return __builtin_amdgcn_exp2f(x); }
__device__ __forceinline__ float fast_rcp(float x)  { return __builtin_amdgcn_rcpf(x); }

// log2(e)
#define L2E 1.4426950408889634f

// ---------------------------------------------------------------------------
// Phase 1: A[t*B+b] = float4 of pre-scaled gate pre-activations.
//   z_g  = x[t,b,:] . W_ih[g,:] + b_ih[g] + b_hh[g]
//   A.x = -z_i*L2E ; A.y = -z_f*L2E ; A.z = -2*z_g*L2E ; A.w = -z_o*L2E
// so phase 2 computes sigmoid(z) = rcp(1+exp2(pre)) directly.
// ---------------------------------------------------------------------------
__global__ __launch_bounds__(256) void lstm_proj(const float* __restrict__ x,
                                                 const float* __restrict__ Wih,
                                                 const float* __restrict__ bih,
                                                 const float* __restrict__ bhh,
                                                 float4* __restrict__ A) {
    // Each block handles 256 consecutive (t,b) positions.
    __shared__ float xs[256 * NIN];             // 27648 B
    const int tid  = threadIdx.x;
    const size_t pos0 = (size_t)blockIdx.x * 256;

    // Stage 256*27 floats = 1728 float4, perfectly coalesced.
    const float4* src4 = (const float4*)(x + pos0 * NIN);
    float4* lds4 = (float4*)xs;
#pragma unroll
    for (int i = 0; i < 6; ++i) lds4[tid + i * 256] = src4[tid + i * 256];
    {
        int idx = tid + 6 * 256;
        if (idx < (256 * NIN) / 4) lds4[idx] = src4[idx];
    }

    // Weights in registers (108 VGPR); uniform across lanes, L1-cached loads.
    float wreg[4 * NIN];
#pragma unroll
    for (int i = 0; i < NIN; ++i) ((float4*)wreg)[i] = ((const float4*)Wih)[i];

    float acc0 = bih[0] + bhh[0];
    float acc1 = bih[1] + bhh[1];
    float acc2 = bih[2] + bhh[2];
    float acc3 = bih[3] + bhh[3];

    __syncthreads();

    // LDS read stride 27 floats: 27 coprime with 32 -> 2-way bank alias (free).
    const float* xr = xs + tid * NIN;
#pragma unroll
    for (int k = 0; k < NIN; ++k) {
        float xv = xr[k];
        acc0 = fmaf(xv, wreg[0 * NIN + k], acc0);
        acc1 = fmaf(xv, wreg[1 * NIN + k], acc1);
        acc2 = fmaf(xv, wreg[2 * NIN + k], acc2);
        acc3 = fmaf(xv, wreg[3 * NIN + k], acc3);
    }

    float4 o;
    o.x = -L2E * acc0;
    o.y = -L2E * acc1;
    o.z = -2.f * L2E * acc2;
    o.w = -L2E * acc3;
    A[pos0 + tid] = o;                          // coalesced float4 store
}

// ---------------------------------------------------------------------------
// Phase 2: 512 independent scalar LSTM chains, one per thread.
// Latency-bound on the loop-carried (h,c) chain; double-buffered 16-step
// register prefetch hides the 16 MB workspace stream (L3/HBM latency).
// All array indices are compile-time constants (no scratch spill).
// ---------------------------------------------------------------------------
#define LSTM_STEP(a4, tt)                                                     \
    {                                                                         \
        float pi = fmaf(h, wi, (a4).x);                                       \
        float pf = fmaf(h, wf, (a4).y);                                       \
        float pg = fmaf(h, wg, (a4).z);                                       \
        float po = fmaf(h, wo, (a4).w);                                       \
        float ri = fast_rcp(1.f + fast_exp2(pi)); /* sigmoid(z_i) */          \
        float rf = fast_rcp(1.f + fast_exp2(pf)); /* sigmoid(z_f) */          \
        float rg = fast_rcp(1.f + fast_exp2(pg)); /* sigmoid(2 z_g) */        \
        float ro = fast_rcp(1.f + fast_exp2(po)); /* sigmoid(z_o) */          \
        float g  = fmaf(rg, 2.f, -1.f);           /* tanh(z_g) */             \
        c = fmaf(rf, c, ri * g);                                              \
        float rc = fast_rcp(1.f + fast_exp2(c * KN));                         \
        float th = fmaf(rc, 2.f, -1.f);           /* tanh(c) */               \
        h = ro * th;                                                          \
        out[(tt) * B_SZ + b] = h;                                             \
    }

__global__ __launch_bounds__(64) void lstm_scan(const float4* __restrict__ A,
                                                const float* __restrict__ Whh,
                                                float* __restrict__ out) {
    const int b = blockIdx.x * 64 + threadIdx.x;   // 0..511

    const float wi = -L2E * Whh[0];
    const float wf = -L2E * Whh[1];
    const float wg = -2.f * L2E * Whh[2];
    const float wo = -L2E * Whh[3];
    const float KN = -2.f * L2E;

    float h = 0.f, c = 0.f;

    constexpr int CH = 16;
    float4 bufA[CH], bufB[CH];

    // Prologue: prefetch steps 0..15.
#pragma unroll
    for (int j = 0; j < CH; ++j) bufA[j] = A[j * B_SZ + b];

    for (int t0 = 0; t0 < T_LEN; t0 += 2 * CH) {
        // Prefetch next chunk while computing current (stays in flight across
        // the dependent-chain compute: ~16*70cy covers HBM-miss latency).
#pragma unroll
        for (int j = 0; j < CH; ++j) bufB[j] = A[(t0 + CH + j) * B_SZ + b];
#pragma unroll
        for (int j = 0; j < CH; ++j) LSTM_STEP(bufA[j], t0 + j);

        if (t0 + 2 * CH < T_LEN) {
#pragma unroll
            for (int j = 0; j < CH; ++j) bufA[j] = A[(t0 + 2 * CH + j) * B_SZ + b];
        }
#pragma unroll
        for (int j = 0; j < CH; ++j) LSTM_STEP(bufB[j], t0 + CH + j);
    }
}

// ---------------------------------------------------------------------------
extern "C" void kernel_launch(void* const* d_in, const int* in_sizes, int n_in,
                              void* d_out, int out_size, void* d_ws, size_t ws_size,
                              hipStream_t stream) {
    const float* x   = (const float*)d_in[0];  // (2048, 512, 27)
    const float* Wih = (const float*)d_in[1];  // (4, 27)
    const float* Whh = (const float*)d_in[2];  // (4, 1)
    const float* bih = (const float*)d_in[3];  // (4,)
    const float* bhh = (const float*)d_in[4];  // (4,)
    float* out = (float*)d_out;                // (2048, 512, 1)
    float4* A  = (float4*)d_ws;                // 16 MB: (T*B) float4

    const int npos = T_LEN * B_SZ;             // 1,048,576
    lstm_proj<<<npos / 256, 256, 0, stream>>>(x, Wih, bih, bhh, A);
    lstm_scan<<<B_SZ / 64, 64, 0, stream>>>(A, Whh, out);
}